// Round 5
// baseline (1140.169 us; speedup 1.0000x reference)
//
#include <hip/hip_runtime.h>
#include <hip/hip_fp16.h>
#include <stdint.h>

// Bidirectional LSTM: N=1024, T=512, H=128; enc 2->128->128; dec 256->128->1.
// fp16 MFMA (fp32 accum). ws = 256 MiB:
//   bufA 128MiB: feat -> overwritten in place with relu(h_fw)   [t][n][128] fp16
//   bufB 128MiB: feat -> overwritten in place with relu(h_bw)   [t][n][128] fp16
// LSTM numerics are EXACTLY round-3's passing version (absmax 2.44e-4); the
// only change is VGPR-pinning the weight fragments via an LDS roundtrip to
// kill the round-3 rematerialization bug (VGPR_Count was 128 == sizeof(wg):
// compiler re-loaded + re-converted all 32 weight frags EVERY step).

#define TN 512
#define NB 1024

typedef __attribute__((ext_vector_type(8))) _Float16 f16x8;
typedef __attribute__((ext_vector_type(4))) float f32x4;

#define MFMA16(a,b,c) __builtin_amdgcn_mfma_f32_16x16x32_f16(a,b,c,0,0,0)

__device__ __forceinline__ f16x8 cvt_frag(const float* p){
  f32x4 a = *(const f32x4*)p;
  f32x4 b = *(const f32x4*)(p+4);
  f16x8 h;
  h[0]=(_Float16)a[0]; h[1]=(_Float16)a[1]; h[2]=(_Float16)a[2]; h[3]=(_Float16)a[3];
  h[4]=(_Float16)b[0]; h[5]=(_Float16)b[1]; h[6]=(_Float16)b[2]; h[7]=(_Float16)b[3];
  return h;
}

__device__ __forceinline__ unsigned short f2h(float f){
  return __half_as_ushort(__float2half(f));
}

// ---------------- K0: encoder -> feat fp16 [t][n][128], written to BOTH copies ----------------
__global__ __launch_bounds__(256) void enc_kernel(
    const float* __restrict__ x,  const float* __restrict__ e1w,
    const float* __restrict__ e1b,const float* __restrict__ e2w,
    const float* __restrict__ e2b,
    unsigned short* __restrict__ featA, unsigned short* __restrict__ featB)
{
  __shared__ float xs[64][2];
  __shared__ unsigned int A32[64][68];   // r1 fp16 pairs, row stride 272B
  int tid = threadIdx.x;
  long rowbase = (long)blockIdx.x * 64;  // row = t*1024 + n
  if (tid < 128){
    int i = tid >> 1, cc = tid & 1;
    long row = rowbase + i;
    int t = (int)(row >> 10), n = (int)(row & 1023);
    xs[i][cc] = x[((size_t)n * TN + t) * 2 + cc];
  }
  int w4 = tid >> 6, lane = tid & 63, lq = lane >> 4, lr = lane & 15;
  f16x8 Bf[2][4];
  float b2v[2];
  #pragma unroll
  for (int nt2 = 0; nt2 < 2; nt2++){
    int col = (w4*2 + nt2)*16 + lr;
    b2v[nt2] = e2b[col];
    #pragma unroll
    for (int ks = 0; ks < 4; ks++)
      Bf[nt2][ks] = cvt_frag(e2w + col*128 + ks*32 + lq*8);
  }
  int q = tid >> 6, dp = tid & 63;
  float w00 = e1w[4*dp], w01 = e1w[4*dp+1], w10 = e1w[4*dp+2], w11 = e1w[4*dp+3];
  float b0 = e1b[2*dp], b1 = e1b[2*dp+1];
  __syncthreads();
  #pragma unroll
  for (int rr = 0; rr < 16; rr++){
    int r = q*16 + rr;
    float x0 = xs[r][0], x1 = xs[r][1];
    float v0 = fmaxf(w00*x0 + w01*x1 + b0, 0.f);
    float v1 = fmaxf(w10*x0 + w11*x1 + b1, 0.f);
    A32[r][dp] = (unsigned int)f2h(v0) | ((unsigned int)f2h(v1) << 16);
  }
  __syncthreads();
  #pragma unroll
  for (int Mt = 0; Mt < 4; Mt++){
    f16x8 ah[4];
    #pragma unroll
    for (int ks = 0; ks < 4; ks++)
      ah[ks] = *(const f16x8*)((const unsigned short*)&A32[Mt*16+lr][0] + ks*32 + lq*8);
    f32x4 acc0 = {0.f,0.f,0.f,0.f}, acc1 = {0.f,0.f,0.f,0.f};
    #pragma unroll
    for (int ks = 0; ks < 4; ks++){
      acc0 = MFMA16(ah[ks], Bf[0][ks], acc0);
      acc1 = MFMA16(ah[ks], Bf[1][ks], acc1);
    }
    #pragma unroll
    for (int r = 0; r < 4; r++){
      size_t row = (size_t)(rowbase + Mt*16 + lq*4 + r);
      unsigned short v0 = f2h(acc0[r] + b2v[0]);
      unsigned short v1 = f2h(acc1[r] + b2v[1]);
      featA[row*128 + (w4*2+0)*16 + lr] = v0;
      featA[row*128 + (w4*2+1)*16 + lr] = v1;
      featB[row*128 + (w4*2+0)*16 + lr] = v0;
      featB[row*128 + (w4*2+1)*16 + lr] = v1;
    }
  }
}

// ---------------- K1: persistent bidirectional LSTM (round-3 structure) ----------------
// 128 blocks x 512 thr; block b: dir=b>>6, samples n0..n0+15.
// Wave w: gate tiles {i,f,g,o} for hidden dims [16w,16w+16); weights VGPR-pinned.
#define LSTM_STEP(P, PFC, PFN) do { \
    int s = 2*s2 + (P); \
    int tt = dir ? (TN-1-s) : s; \
    f16x8 ah[4]; \
    _Pragma("unroll") \
    for (int ks = 0; ks < 4; ks++) ah[ks] = *(const f16x8*)&hbS[P][lr][ks*32 + lq*8]; \
    { int tnn = dir ? (TN-2-s) : (s+1); \
      tnn = tnn < 0 ? 0 : (tnn > TN-1 ? TN-1 : tnn); \
      const unsigned short* fb = buf + ((size_t)tnn*NB + n0 + lr)*128 + lq*8; \
      _Pragma("unroll") \
      for (int ks = 0; ks < 4; ks++) PFN[ks] = *(const uint4*)(fb + ks*32); } \
    f32x4 acc[4]; \
    _Pragma("unroll") \
    for (int G = 0; G < 4; G++) acc[G] = (f32x4){0.f,0.f,0.f,0.f}; \
    _Pragma("unroll") \
    for (int ks = 0; ks < 4; ks++){ \
      _Pragma("unroll") \
      for (int G = 0; G < 4; G++) acc[G] = MFMA16(*(const f16x8*)&PFC[ks], wg[G][ks], acc[G]); \
    } \
    _Pragma("unroll") \
    for (int ks = 0; ks < 4; ks++){ \
      _Pragma("unroll") \
      for (int G = 0; G < 4; G++) acc[G] = MFMA16(ah[ks], wg[G][4+ks], acc[G]); \
    } \
    _Pragma("unroll") \
    for (int r = 0; r < 4; r++){ \
      float iv = acc[0][r], fv = acc[1][r], gv = acc[2][r], ov = acc[3][r]; \
      float si = 1.f/(1.f + __expf(-iv)); \
      float sf = 1.f/(1.f + __expf(-fv)); \
      float tg = 1.f - 2.f/(__expf(2.f*gv) + 1.f); \
      float so = 1.f/(1.f + __expf(-ov)); \
      c[r] = sf*c[r] + si*tg; \
      float tc = 1.f - 2.f/(__expf(2.f*c[r]) + 1.f); \
      float hv = so*tc; \
      int sm = lq*4 + r; \
      hbS[(P)^1][sm][w*16 + lr] = f2h(hv); \
      buf[((size_t)tt*NB + n0 + sm)*128 + w*16 + lr] = f2h(fmaxf(hv, 0.f)); \
    } \
    __syncthreads(); \
  } while(0)

__global__ __launch_bounds__(512, 2) void lstm_kernel(
    unsigned short* bufA, unsigned short* bufB,
    const float* __restrict__ wih, const float* __restrict__ whh)
{
  __shared__ __align__(16) unsigned short hbS[2][16][136];   // h double-buffer, row stride 272B
  int tid = threadIdx.x, b = blockIdx.x;
  int dir = b >> 6, n0 = (b & 63) << 4;
  int w = tid >> 6, lane = tid & 63, lq = lane >> 4, lr = lane & 15;
  unsigned short* buf = dir ? bufB : bufA;

  // --- weight fragments fp32->fp16, VGPR-PINNED via LDS roundtrip ---
  // Each thread writes its frag to its own 16B LDS slot and reads it back
  // across barriers. The slots are clobbered below (h staging), so the
  // compiler can neither store-forward nor rematerialize: wg stays in VGPRs.
  // (Round-3 bug: without this, VGPR=128 and weights were re-loaded +
  // re-converted from fp32 every one of the 512 steps.)
  f16x8 wg[4][8];
  {
    uint4* sl = (uint4*)hbS;           // 544 slots of 16B >= 512 threads
    #pragma unroll
    for (int G = 0; G < 4; G++){
      #pragma unroll
      for (int ks = 0; ks < 8; ks++){
        int gate = G*128 + w*16 + lr;
        const float* src = (ks < 4) ? (wih + (size_t)gate*128 + ks*32 + lq*8)
                                    : (whh + (size_t)gate*128 + (ks-4)*32 + lq*8);
        f16x8 tf = cvt_frag(src);
        __syncthreads();               // previous iteration's readers done
        sl[tid] = *(uint4*)&tf;
        __syncthreads();               // writes visible; forwarding illegal
        wg[G][ks] = *(const f16x8*)&sl[tid];
      }
    }
  }
  __syncthreads();                     // all readbacks done before clobbering

  for (int i = tid; i < 2176; i += 512) ((unsigned int*)hbS)[i] = 0u;

  float c[4] = {0.f, 0.f, 0.f, 0.f};
  uint4 pfA[4], pfB[4];
  {
    int t0 = dir ? (TN-1) : 0;
    const unsigned short* fb = buf + ((size_t)t0*NB + n0 + lr)*128 + lq*8;
    #pragma unroll
    for (int ks = 0; ks < 4; ks++) pfA[ks] = *(const uint4*)(fb + ks*32);
  }
  __syncthreads();
  for (int s2 = 0; s2 < TN/2; s2++){
    LSTM_STEP(0, pfA, pfB);
    LSTM_STEP(1, pfB, pfA);
  }
}

// ---------------- K2: decoder (fp16 MFMA, K=256); inputs already relu'd ----------------
__global__ __launch_bounds__(256) void dec_kernel(
    const unsigned short* __restrict__ hfw, const unsigned short* __restrict__ hbw,
    const float* __restrict__ d1w, const float* __restrict__ d1b,
    const float* __restrict__ d2w, const float* __restrict__ d2b,
    float* __restrict__ out)
{
  __shared__ unsigned short A[64][264];  // [hfw||hbw], row stride 528B
  __shared__ float partial[4][64];
  int tid = threadIdx.x;
  long rowbase = (long)blockIdx.x * 64;
  #pragma unroll
  for (int u = 0; u < 8; u++){
    int chunk = u*256 + tid;             // 0..2047
    int row = chunk >> 5, seg = chunk & 31;
    const unsigned short* src = (seg < 16)
        ? (hfw + ((size_t)(rowbase + row))*128 + seg*8)
        : (hbw + ((size_t)(rowbase + row))*128 + (seg-16)*8);
    *(uint4*)&A[row][seg*8] = *(const uint4*)src;
  }
  int w4 = tid >> 6, lane = tid & 63, lq = lane >> 4, lr = lane & 15;
  f16x8 Bf[2][8];
  float b1v[2], w2v[2];
  #pragma unroll
  for (int nt2 = 0; nt2 < 2; nt2++){
    int col = (w4*2 + nt2)*16 + lr;
    b1v[nt2] = d1b[col];
    w2v[nt2] = d2w[col];
    #pragma unroll
    for (int ks = 0; ks < 8; ks++)
      Bf[nt2][ks] = cvt_frag(d1w + col*256 + ks*32 + lq*8);
  }
  float b2s = d2b[0];
  __syncthreads();
  #pragma unroll
  for (int Mt = 0; Mt < 4; Mt++){
    f16x8 ah[8];
    #pragma unroll
    for (int ks = 0; ks < 8; ks++)
      ah[ks] = *(const f16x8*)&A[Mt*16+lr][ks*32 + lq*8];
    f32x4 acc0 = {0.f,0.f,0.f,0.f}, acc1 = {0.f,0.f,0.f,0.f};
    #pragma unroll
    for (int ks = 0; ks < 8; ks++){
      acc0 = MFMA16(ah[ks], Bf[0][ks], acc0);
      acc1 = MFMA16(ah[ks], Bf[1][ks], acc1);
    }
    #pragma unroll
    for (int r = 0; r < 4; r++){
      float p = fmaxf(acc0[r] + b1v[0], 0.f) * w2v[0]
              + fmaxf(acc1[r] + b1v[1], 0.f) * w2v[1];
      p += __shfl_xor(p, 1);
      p += __shfl_xor(p, 2);
      p += __shfl_xor(p, 4);
      p += __shfl_xor(p, 8);
      if (lr == 0) partial[w4][Mt*16 + lq*4 + r] = p;
    }
  }
  __syncthreads();
  if (tid < 64){
    long row = rowbase + tid;
    int t = (int)(row >> 10), n = (int)(row & 1023);
    out[(size_t)n*TN + t] = partial[0][tid] + partial[1][tid]
                          + partial[2][tid] + partial[3][tid] + b2s;
  }
}

extern "C" void kernel_launch(void* const* d_in, const int* in_sizes, int n_in,
                              void* d_out, int out_size, void* d_ws, size_t ws_size,
                              hipStream_t stream)
{
  const float* x   = (const float*)d_in[0];
  const float* e1w = (const float*)d_in[1];
  const float* e1b = (const float*)d_in[2];
  const float* e2w = (const float*)d_in[3];
  const float* e2b = (const float*)d_in[4];
  const float* wih = (const float*)d_in[5];
  const float* whh = (const float*)d_in[6];
  const float* d1w = (const float*)d_in[7];
  const float* d1b = (const float*)d_in[8];
  const float* d2w = (const float*)d_in[9];
  const float* d2b = (const float*)d_in[10];
  float* out = (float*)d_out;

  if (ws_size < ((size_t)256 << 20)) return;   // ws guard (rounds 1-2 crashed on ws overflow)

  char* ws = (char*)d_ws;
  unsigned short* bufA = (unsigned short*)ws;                            // 128 MiB
  unsigned short* bufB = (unsigned short*)(ws + (((size_t)128) << 20));  // 128 MiB

  hipLaunchKernelGGL(enc_kernel, dim3(8192), dim3(256), 0, stream, x, e1w, e1b, e2w, e2b, bufA, bufB);
  hipLaunchKernelGGL(lstm_kernel, dim3(128), dim3(512), 0, stream, bufA, bufB, wih, whh);
  hipLaunchKernelGGL(dec_kernel, dim3(8192), dim3(256), 0, stream, bufA, bufB, d1w, d1b, d2w, d2b, out);
}

// Round 6
// 836.972 us; speedup vs baseline: 1.3623x; 1.3623x over previous
//
#include <hip/hip_runtime.h>
#include <hip/hip_fp16.h>
#include <stdint.h>

// Bidirectional LSTM: N=1024, T=512, H=128; enc 2->128->128; dec 256->128->1.
// fp16 MFMA (fp32 accum). ws = 256 MiB:
//   bufA 128MiB: feat -> overwritten in place with relu(h_fw)   [t][n][128] fp16
//   bufB 128MiB: feat -> overwritten in place with relu(h_bw)   [t][n][128] fp16
// LSTM: 256 blocks x 512 thr, 8 samples/block (2x CU utilization vs round 5,
// halved per-lane elementwise). Numerics per sample bit-identical to the
// passing round-5 kernel; ONLY change is the sample<->MFMA-row packing:
//   A/C rows {0,1,4,5,8,9,12,13} carry samples 0..7 (row R -> sample
//   ((R>>2)<<1)|(R&1)); acc regs r in {0,1} at lane group lq give sample
//   lq*2+r (C row lq*4+r). Rows 2,3,6,7,... are don't-care duplicates.

#define TN 512
#define NB 1024

typedef __attribute__((ext_vector_type(8))) _Float16 f16x8;
typedef __attribute__((ext_vector_type(4))) float f32x4;

#define MFMA16(a,b,c) __builtin_amdgcn_mfma_f32_16x16x32_f16(a,b,c,0,0,0)

__device__ __forceinline__ f16x8 cvt_frag(const float* p){
  f32x4 a = *(const f32x4*)p;
  f32x4 b = *(const f32x4*)(p+4);
  f16x8 h;
  h[0]=(_Float16)a[0]; h[1]=(_Float16)a[1]; h[2]=(_Float16)a[2]; h[3]=(_Float16)a[3];
  h[4]=(_Float16)b[0]; h[5]=(_Float16)b[1]; h[6]=(_Float16)b[2]; h[7]=(_Float16)b[3];
  return h;
}

__device__ __forceinline__ unsigned short f2h(float f){
  return __half_as_ushort(__float2half(f));
}

// ---------------- K0: encoder -> feat fp16 [t][n][128], written to BOTH copies ----------------
__global__ __launch_bounds__(256) void enc_kernel(
    const float* __restrict__ x,  const float* __restrict__ e1w,
    const float* __restrict__ e1b,const float* __restrict__ e2w,
    const float* __restrict__ e2b,
    unsigned short* __restrict__ featA, unsigned short* __restrict__ featB)
{
  __shared__ float xs[64][2];
  __shared__ unsigned int A32[64][68];   // r1 fp16 pairs, row stride 272B
  int tid = threadIdx.x;
  long rowbase = (long)blockIdx.x * 64;  // row = t*1024 + n
  if (tid < 128){
    int i = tid >> 1, cc = tid & 1;
    long row = rowbase + i;
    int t = (int)(row >> 10), n = (int)(row & 1023);
    xs[i][cc] = x[((size_t)n * TN + t) * 2 + cc];
  }
  int w4 = tid >> 6, lane = tid & 63, lq = lane >> 4, lr = lane & 15;
  f16x8 Bf[2][4];
  float b2v[2];
  #pragma unroll
  for (int nt2 = 0; nt2 < 2; nt2++){
    int col = (w4*2 + nt2)*16 + lr;
    b2v[nt2] = e2b[col];
    #pragma unroll
    for (int ks = 0; ks < 4; ks++)
      Bf[nt2][ks] = cvt_frag(e2w + col*128 + ks*32 + lq*8);
  }
  int q = tid >> 6, dp = tid & 63;
  float w00 = e1w[4*dp], w01 = e1w[4*dp+1], w10 = e1w[4*dp+2], w11 = e1w[4*dp+3];
  float b0 = e1b[2*dp], b1 = e1b[2*dp+1];
  __syncthreads();
  #pragma unroll
  for (int rr = 0; rr < 16; rr++){
    int r = q*16 + rr;
    float x0 = xs[r][0], x1 = xs[r][1];
    float v0 = fmaxf(w00*x0 + w01*x1 + b0, 0.f);
    float v1 = fmaxf(w10*x0 + w11*x1 + b1, 0.f);
    A32[r][dp] = (unsigned int)f2h(v0) | ((unsigned int)f2h(v1) << 16);
  }
  __syncthreads();
  #pragma unroll
  for (int Mt = 0; Mt < 4; Mt++){
    f16x8 ah[4];
    #pragma unroll
    for (int ks = 0; ks < 4; ks++)
      ah[ks] = *(const f16x8*)((const unsigned short*)&A32[Mt*16+lr][0] + ks*32 + lq*8);
    f32x4 acc0 = {0.f,0.f,0.f,0.f}, acc1 = {0.f,0.f,0.f,0.f};
    #pragma unroll
    for (int ks = 0; ks < 4; ks++){
      acc0 = MFMA16(ah[ks], Bf[0][ks], acc0);
      acc1 = MFMA16(ah[ks], Bf[1][ks], acc1);
    }
    #pragma unroll
    for (int r = 0; r < 4; r++){
      size_t row = (size_t)(rowbase + Mt*16 + lq*4 + r);
      unsigned short v0 = f2h(acc0[r] + b2v[0]);
      unsigned short v1 = f2h(acc1[r] + b2v[1]);
      featA[row*128 + (w4*2+0)*16 + lr] = v0;
      featA[row*128 + (w4*2+1)*16 + lr] = v1;
      featB[row*128 + (w4*2+0)*16 + lr] = v0;
      featB[row*128 + (w4*2+1)*16 + lr] = v1;
    }
  }
}

// ---------------- K1: persistent bidirectional LSTM ----------------
// 256 blocks x 512 thr; block b: dir=b>>7, samples n0..n0+7.
// Wave w: gate tiles {i,f,g,o} for hidden dims [16w,16w+16); weights resident.
#define LSTM_STEP(P, PFC, PFN) do { \
    int s = 2*s2 + (P); \
    int tt = dir ? (TN-1-s) : s; \
    f16x8 ah[4]; \
    _Pragma("unroll") \
    for (int ks = 0; ks < 4; ks++) ah[ks] = *(const f16x8*)&hbS[P][smr][ks*32 + lq*8]; \
    { int tnn = dir ? (TN-2-s) : (s+1); \
      tnn = tnn < 0 ? 0 : (tnn > TN-1 ? TN-1 : tnn); \
      const unsigned short* fb = buf + ((size_t)tnn*NB + n0 + smr)*128 + lq*8; \
      _Pragma("unroll") \
      for (int ks = 0; ks < 4; ks++) PFN[ks] = *(const uint4*)(fb + ks*32); } \
    f32x4 acc[4]; \
    _Pragma("unroll") \
    for (int G = 0; G < 4; G++) acc[G] = (f32x4){0.f,0.f,0.f,0.f}; \
    _Pragma("unroll") \
    for (int ks = 0; ks < 4; ks++){ \
      _Pragma("unroll") \
      for (int G = 0; G < 4; G++) acc[G] = MFMA16(*(const f16x8*)&PFC[ks], wg[G][ks], acc[G]); \
    } \
    _Pragma("unroll") \
    for (int ks = 0; ks < 4; ks++){ \
      _Pragma("unroll") \
      for (int G = 0; G < 4; G++) acc[G] = MFMA16(ah[ks], wg[G][4+ks], acc[G]); \
    } \
    _Pragma("unroll") \
    for (int r = 0; r < 2; r++){ \
      float iv = acc[0][r], fv = acc[1][r], gv = acc[2][r], ov = acc[3][r]; \
      float si = 1.f/(1.f + __expf(-iv)); \
      float sf = 1.f/(1.f + __expf(-fv)); \
      float tg = 1.f - 2.f/(__expf(2.f*gv) + 1.f); \
      float so = 1.f/(1.f + __expf(-ov)); \
      c[r] = sf*c[r] + si*tg; \
      float tc = 1.f - 2.f/(__expf(2.f*c[r]) + 1.f); \
      float hv = so*tc; \
      int sm = lq*2 + r; \
      hbS[(P)^1][sm][w*16 + lr] = f2h(hv); \
      buf[((size_t)tt*NB + n0 + sm)*128 + w*16 + lr] = f2h(fmaxf(hv, 0.f)); \
    } \
    __syncthreads(); \
  } while(0)

__global__ __launch_bounds__(512, 2) void lstm_kernel(
    unsigned short* bufA, unsigned short* bufB,
    const float* __restrict__ wih, const float* __restrict__ whh)
{
  __shared__ __align__(16) unsigned short hbS[2][8][136];   // h double-buffer, 4352 B
  __shared__ __align__(16) uint4 wslots[512];               // weight roundtrip slab
  int tid = threadIdx.x, b = blockIdx.x;
  int dir = b >> 7, n0 = (b & 127) << 3;
  int w = tid >> 6, lane = tid & 63, lq = lane >> 4, lr = lane & 15;
  unsigned short* buf = dir ? bufB : bufA;

  // --- weight fragments fp32->fp16, VGPR/AGPR-pinned via LDS roundtrip ---
  f16x8 wg[4][8];
  {
    #pragma unroll
    for (int G = 0; G < 4; G++){
      #pragma unroll
      for (int ks = 0; ks < 8; ks++){
        int gate = G*128 + w*16 + lr;
        const float* src = (ks < 4) ? (wih + (size_t)gate*128 + ks*32 + lq*8)
                                    : (whh + (size_t)gate*128 + (ks-4)*32 + lq*8);
        f16x8 tf = cvt_frag(src);
        __syncthreads();
        wslots[tid] = *(uint4*)&tf;
        __syncthreads();
        wg[G][ks] = *(const f16x8*)&wslots[tid];
      }
    }
    // same-address clobber: the last readback cannot be sunk past this store,
    // so wg must materialize in registers before the step loop.
    wslots[tid] = (uint4){0u,0u,0u,0u};
  }

  for (int i = tid; i < 1088; i += 512) ((unsigned int*)hbS)[i] = 0u;

  // A-row R carries sample ((R>>2)<<1)|(R&1); this lane reads A row lr.
  int smr = ((lr >> 2) << 1) | (lr & 1);
  float c[2] = {0.f, 0.f};
  uint4 pfA[4], pfB[4];
  {
    int t0 = dir ? (TN-1) : 0;
    const unsigned short* fb = buf + ((size_t)t0*NB + n0 + smr)*128 + lq*8;
    #pragma unroll
    for (int ks = 0; ks < 4; ks++) pfA[ks] = *(const uint4*)(fb + ks*32);
  }
  __syncthreads();
  for (int s2 = 0; s2 < TN/2; s2++){
    LSTM_STEP(0, pfA, pfB);
    LSTM_STEP(1, pfB, pfA);
  }
}

// ---------------- K2: decoder (fp16 MFMA, K=256); inputs already relu'd ----------------
__global__ __launch_bounds__(256) void dec_kernel(
    const unsigned short* __restrict__ hfw, const unsigned short* __restrict__ hbw,
    const float* __restrict__ d1w, const float* __restrict__ d1b,
    const float* __restrict__ d2w, const float* __restrict__ d2b,
    float* __restrict__ out)
{
  __shared__ unsigned short A[64][264];  // [hfw||hbw], row stride 528B
  __shared__ float partial[4][64];
  int tid = threadIdx.x;
  long rowbase = (long)blockIdx.x * 64;
  #pragma unroll
  for (int u = 0; u < 8; u++){
    int chunk = u*256 + tid;             // 0..2047
    int row = chunk >> 5, seg = chunk & 31;
    const unsigned short* src = (seg < 16)
        ? (hfw + ((size_t)(rowbase + row))*128 + seg*8)
        : (hbw + ((size_t)(rowbase + row))*128 + (seg-16)*8);
    *(uint4*)&A[row][seg*8] = *(const uint4*)src;
  }
  int w4 = tid >> 6, lane = tid & 63, lq = lane >> 4, lr = lane & 15;
  f16x8 Bf[2][8];
  float b1v[2], w2v[2];
  #pragma unroll
  for (int nt2 = 0; nt2 < 2; nt2++){
    int col = (w4*2 + nt2)*16 + lr;
    b1v[nt2] = d1b[col];
    w2v[nt2] = d2w[col];
    #pragma unroll
    for (int ks = 0; ks < 8; ks++)
      Bf[nt2][ks] = cvt_frag(d1w + col*256 + ks*32 + lq*8);
  }
  float b2s = d2b[0];
  __syncthreads();
  #pragma unroll
  for (int Mt = 0; Mt < 4; Mt++){
    f16x8 ah[8];
    #pragma unroll
    for (int ks = 0; ks < 8; ks++)
      ah[ks] = *(const f16x8*)&A[Mt*16+lr][ks*32 + lq*8];
    f32x4 acc0 = {0.f,0.f,0.f,0.f}, acc1 = {0.f,0.f,0.f,0.f};
    #pragma unroll
    for (int ks = 0; ks < 8; ks++){
      acc0 = MFMA16(ah[ks], Bf[0][ks], acc0);
      acc1 = MFMA16(ah[ks], Bf[1][ks], acc1);
    }
    #pragma unroll
    for (int r = 0; r < 4; r++){
      float p = fmaxf(acc0[r] + b1v[0], 0.f) * w2v[0]
              + fmaxf(acc1[r] + b1v[1], 0.f) * w2v[1];
      p += __shfl_xor(p, 1);
      p += __shfl_xor(p, 2);
      p += __shfl_xor(p, 4);
      p += __shfl_xor(p, 8);
      if (lr == 0) partial[w4][Mt*16 + lq*4 + r] = p;
    }
  }
  __syncthreads();
  if (tid < 64){
    long row = rowbase + tid;
    int t = (int)(row >> 10), n = (int)(row & 1023);
    out[(size_t)n*TN + t] = partial[0][tid] + partial[1][tid]
                          + partial[2][tid] + partial[3][tid] + b2s;
  }
}

extern "C" void kernel_launch(void* const* d_in, const int* in_sizes, int n_in,
                              void* d_out, int out_size, void* d_ws, size_t ws_size,
                              hipStream_t stream)
{
  const float* x   = (const float*)d_in[0];
  const float* e1w = (const float*)d_in[1];
  const float* e1b = (const float*)d_in[2];
  const float* e2w = (const float*)d_in[3];
  const float* e2b = (const float*)d_in[4];
  const float* wih = (const float*)d_in[5];
  const float* whh = (const float*)d_in[6];
  const float* d1w = (const float*)d_in[7];
  const float* d1b = (const float*)d_in[8];
  const float* d2w = (const float*)d_in[9];
  const float* d2b = (const float*)d_in[10];
  float* out = (float*)d_out;

  if (ws_size < ((size_t)256 << 20)) return;   // ws guard (rounds 1-2 crashed on ws overflow)

  char* ws = (char*)d_ws;
  unsigned short* bufA = (unsigned short*)ws;                            // 128 MiB
  unsigned short* bufB = (unsigned short*)(ws + (((size_t)128) << 20));  // 128 MiB

  hipLaunchKernelGGL(enc_kernel, dim3(8192), dim3(256), 0, stream, x, e1w, e1b, e2w, e2b, bufA, bufB);
  hipLaunchKernelGGL(lstm_kernel, dim3(256), dim3(512), 0, stream, bufA, bufB, wih, whh);
  hipLaunchKernelGGL(dec_kernel, dim3(8192), dim3(256), 0, stream, bufA, bufB, d1w, d1b, d2w, d2b, out);
}

// Round 7
// 680.007 us; speedup vs baseline: 1.6767x; 1.2308x over previous
//
#include <hip/hip_runtime.h>
#include <hip/hip_fp16.h>
#include <stdint.h>

// Bidirectional LSTM: N=1024, T=512, H=128; enc 2->128->128; dec 256->128->1.
// fp16 MFMA (fp32 accum). ws = 256 MiB:
//   bufA 128MiB: feat -> overwritten in place with relu(h_fw)   [t][n][128] fp16
//   bufB 128MiB: feat -> overwritten in place with relu(h_bw)   [t][n][128] fp16
// LSTM: 256 blocks x 512 thr, 8 samples/block. Same packing as round 6
// (A/C rows {0,1,4,5,...} carry samples; acc r=0,1 -> sample lq*2+r).
// Round-7: issue-count diet — rcp-based sigmoid/tanh (no IEEE div), running
// pointers (no per-step addr recompute/clamp; boundary over-reads land in the
// adjacent ws buffer and are dead), zero-C first MFMA, single f2h + bit-select
// relu store.

#define TN 512
#define NB 1024

typedef __attribute__((ext_vector_type(8))) _Float16 f16x8;
typedef __attribute__((ext_vector_type(4))) float f32x4;

#define MFMA16(a,b,c) __builtin_amdgcn_mfma_f32_16x16x32_f16(a,b,c,0,0,0)
#define RCP(x) __builtin_amdgcn_rcpf(x)

__device__ __forceinline__ f16x8 cvt_frag(const float* p){
  f32x4 a = *(const f32x4*)p;
  f32x4 b = *(const f32x4*)(p+4);
  f16x8 h;
  h[0]=(_Float16)a[0]; h[1]=(_Float16)a[1]; h[2]=(_Float16)a[2]; h[3]=(_Float16)a[3];
  h[4]=(_Float16)b[0]; h[5]=(_Float16)b[1]; h[6]=(_Float16)b[2]; h[7]=(_Float16)b[3];
  return h;
}

__device__ __forceinline__ unsigned short f2h(float f){
  return __half_as_ushort(__float2half(f));
}

// ---------------- K0: encoder -> feat fp16 [t][n][128], written to BOTH copies ----------------
__global__ __launch_bounds__(256) void enc_kernel(
    const float* __restrict__ x,  const float* __restrict__ e1w,
    const float* __restrict__ e1b,const float* __restrict__ e2w,
    const float* __restrict__ e2b,
    unsigned short* __restrict__ featA, unsigned short* __restrict__ featB)
{
  __shared__ float xs[64][2];
  __shared__ unsigned int A32[64][68];   // r1 fp16 pairs, row stride 272B
  int tid = threadIdx.x;
  long rowbase = (long)blockIdx.x * 64;  // row = t*1024 + n
  if (tid < 128){
    int i = tid >> 1, cc = tid & 1;
    long row = rowbase + i;
    int t = (int)(row >> 10), n = (int)(row & 1023);
    xs[i][cc] = x[((size_t)n * TN + t) * 2 + cc];
  }
  int w4 = tid >> 6, lane = tid & 63, lq = lane >> 4, lr = lane & 15;
  f16x8 Bf[2][4];
  float b2v[2];
  #pragma unroll
  for (int nt2 = 0; nt2 < 2; nt2++){
    int col = (w4*2 + nt2)*16 + lr;
    b2v[nt2] = e2b[col];
    #pragma unroll
    for (int ks = 0; ks < 4; ks++)
      Bf[nt2][ks] = cvt_frag(e2w + col*128 + ks*32 + lq*8);
  }
  int q = tid >> 6, dp = tid & 63;
  float w00 = e1w[4*dp], w01 = e1w[4*dp+1], w10 = e1w[4*dp+2], w11 = e1w[4*dp+3];
  float b0 = e1b[2*dp], b1 = e1b[2*dp+1];
  __syncthreads();
  #pragma unroll
  for (int rr = 0; rr < 16; rr++){
    int r = q*16 + rr;
    float x0 = xs[r][0], x1 = xs[r][1];
    float v0 = fmaxf(w00*x0 + w01*x1 + b0, 0.f);
    float v1 = fmaxf(w10*x0 + w11*x1 + b1, 0.f);
    A32[r][dp] = (unsigned int)f2h(v0) | ((unsigned int)f2h(v1) << 16);
  }
  __syncthreads();
  #pragma unroll
  for (int Mt = 0; Mt < 4; Mt++){
    f16x8 ah[4];
    #pragma unroll
    for (int ks = 0; ks < 4; ks++)
      ah[ks] = *(const f16x8*)((const unsigned short*)&A32[Mt*16+lr][0] + ks*32 + lq*8);
    f32x4 acc0 = {0.f,0.f,0.f,0.f}, acc1 = {0.f,0.f,0.f,0.f};
    #pragma unroll
    for (int ks = 0; ks < 4; ks++){
      acc0 = MFMA16(ah[ks], Bf[0][ks], acc0);
      acc1 = MFMA16(ah[ks], Bf[1][ks], acc1);
    }
    #pragma unroll
    for (int r = 0; r < 4; r++){
      size_t row = (size_t)(rowbase + Mt*16 + lq*4 + r);
      unsigned short v0 = f2h(acc0[r] + b2v[0]);
      unsigned short v1 = f2h(acc1[r] + b2v[1]);
      featA[row*128 + (w4*2+0)*16 + lr] = v0;
      featA[row*128 + (w4*2+1)*16 + lr] = v1;
      featB[row*128 + (w4*2+0)*16 + lr] = v0;
      featB[row*128 + (w4*2+1)*16 + lr] = v1;
    }
  }
}

// ---------------- K1: persistent bidirectional LSTM ----------------
// 256 blocks x 512 thr; block b: dir=b>>7, samples n0..n0+7.
// Wave w: gate tiles {i,f,g,o} for hidden dims [16w,16w+16); weights resident.
#define LSTM_STEP(P, PFC, PFN) do { \
    f16x8 ah[4]; \
    _Pragma("unroll") \
    for (int ks = 0; ks < 4; ks++) ah[ks] = *(const f16x8*)&hbS[P][smr][ks*32 + lq*8]; \
    _Pragma("unroll") \
    for (int ks = 0; ks < 4; ks++) PFN[ks] = *(const uint4*)(fpp + ks*32); \
    fpp += dstep; \
    f32x4 acc[4]; \
    _Pragma("unroll") \
    for (int G = 0; G < 4; G++) acc[G] = MFMA16(*(const f16x8*)&PFC[0], wg[G][0], zero4); \
    _Pragma("unroll") \
    for (int ks = 1; ks < 4; ks++){ \
      _Pragma("unroll") \
      for (int G = 0; G < 4; G++) acc[G] = MFMA16(*(const f16x8*)&PFC[ks], wg[G][ks], acc[G]); \
    } \
    _Pragma("unroll") \
    for (int ks = 0; ks < 4; ks++){ \
      _Pragma("unroll") \
      for (int G = 0; G < 4; G++) acc[G] = MFMA16(ah[ks], wg[G][4+ks], acc[G]); \
    } \
    _Pragma("unroll") \
    for (int r = 0; r < 2; r++){ \
      float iv = acc[0][r], fv = acc[1][r], gv = acc[2][r], ov = acc[3][r]; \
      float si = RCP(1.f + __expf(-iv)); \
      float sf = RCP(1.f + __expf(-fv)); \
      float so = RCP(1.f + __expf(-ov)); \
      float tg = 1.f - 2.f*RCP(__expf(2.f*gv) + 1.f); \
      c[r] = sf*c[r] + si*tg; \
      float tc = 1.f - 2.f*RCP(__expf(2.f*c[r]) + 1.f); \
      float hv = so*tc; \
      unsigned short hh = f2h(hv); \
      hbS[(P)^1][lq*2+r][w*16 + lr] = hh; \
      op[r*128] = (hv > 0.f) ? hh : (unsigned short)0; \
    } \
    op += dstep; \
    __syncthreads(); \
  } while(0)

__global__ __launch_bounds__(512, 2) void lstm_kernel(
    unsigned short* bufA, unsigned short* bufB,
    const float* __restrict__ wih, const float* __restrict__ whh)
{
  __shared__ __align__(16) unsigned short hbS[2][8][136];   // h double-buffer, 4352 B
  int tid = threadIdx.x, b = blockIdx.x;
  int dir = b >> 7, n0 = (b & 127) << 3;
  int w = tid >> 6, lane = tid & 63, lq = lane >> 4, lr = lane & 15;
  unsigned short* buf = dir ? bufB : bufA;

  // resident fp16 weight fragments: k 0..127 = w_ih (feat), 128..255 = w_hh (h)
  f16x8 wg[4][8];
  #pragma unroll
  for (int G = 0; G < 4; G++){
    int gate = G*128 + w*16 + lr;
    #pragma unroll
    for (int ks = 0; ks < 8; ks++){
      const float* src = (ks < 4) ? (wih + (size_t)gate*128 + ks*32 + lq*8)
                                  : (whh + (size_t)gate*128 + (ks-4)*32 + lq*8);
      wg[G][ks] = cvt_frag(src);
    }
  }

  for (int i = tid; i < 1088; i += 512) ((unsigned int*)hbS)[i] = 0u;

  // A-row R carries sample ((R>>2)<<1)|(R&1); this lane reads A row lr.
  int smr = ((lr >> 2) << 1) | (lr & 1);
  float c[2] = {0.f, 0.f};
  const f32x4 zero4 = {0.f, 0.f, 0.f, 0.f};
  int t0 = dir ? (TN-1) : 0;
  long dstep = dir ? -(long)(NB*128) : (long)(NB*128);

  // running feat-prefetch pointer (this lane's A-row smr, k-chunk base lq*8)
  const unsigned short* fpp = buf + ((size_t)t0*NB + n0 + smr)*128 + lq*8;
  uint4 pfA[4], pfB[4];
  #pragma unroll
  for (int ks = 0; ks < 4; ks++) pfA[ks] = *(const uint4*)(fpp + ks*32);
  fpp += dstep;
  // Boundary over-reads on the final prefetches stay inside ws:
  //   fw: bufA + (512)*256KB == start of bufB; bw: bufB - 256KB == end of bufA.
  // Those loaded values are never consumed (loop ends first).

  // running output pointer: sample lq*2 (+1 via imm offset 128), dim w*16+lr
  unsigned short* op = buf + ((size_t)t0*NB + n0 + lq*2)*128 + (w*16 + lr);
  __syncthreads();

  for (int s2 = 0; s2 < TN/2; s2++){
    LSTM_STEP(0, pfA, pfB);
    LSTM_STEP(1, pfB, pfA);
  }
}

// ---------------- K2: decoder (fp16 MFMA, K=256); inputs already relu'd ----------------
__global__ __launch_bounds__(256) void dec_kernel(
    const unsigned short* __restrict__ hfw, const unsigned short* __restrict__ hbw,
    const float* __restrict__ d1w, const float* __restrict__ d1b,
    const float* __restrict__ d2w, const float* __restrict__ d2b,
    float* __restrict__ out)
{
  __shared__ unsigned short A[64][264];  // [hfw||hbw], row stride 528B
  __shared__ float partial[4][64];
  int tid = threadIdx.x;
  long rowbase = (long)blockIdx.x * 64;
  #pragma unroll
  for (int u = 0; u < 8; u++){
    int chunk = u*256 + tid;             // 0..2047
    int row = chunk >> 5, seg = chunk & 31;
    const unsigned short* src = (seg < 16)
        ? (hfw + ((size_t)(rowbase + row))*128 + seg*8)
        : (hbw + ((size_t)(rowbase + row))*128 + (seg-16)*8);
    *(uint4*)&A[row][seg*8] = *(const uint4*)src;
  }
  int w4 = tid >> 6, lane = tid & 63, lq = lane >> 4, lr = lane & 15;
  f16x8 Bf[2][8];
  float b1v[2], w2v[2];
  #pragma unroll
  for (int nt2 = 0; nt2 < 2; nt2++){
    int col = (w4*2 + nt2)*16 + lr;
    b1v[nt2] = d1b[col];
    w2v[nt2] = d2w[col];
    #pragma unroll
    for (int ks = 0; ks < 8; ks++)
      Bf[nt2][ks] = cvt_frag(d1w + col*256 + ks*32 + lq*8);
  }
  float b2s = d2b[0];
  __syncthreads();
  #pragma unroll
  for (int Mt = 0; Mt < 4; Mt++){
    f16x8 ah[8];
    #pragma unroll
    for (int ks = 0; ks < 8; ks++)
      ah[ks] = *(const f16x8*)&A[Mt*16+lr][ks*32 + lq*8];
    f32x4 acc0 = {0.f,0.f,0.f,0.f}, acc1 = {0.f,0.f,0.f,0.f};
    #pragma unroll
    for (int ks = 0; ks < 8; ks++){
      acc0 = MFMA16(ah[ks], Bf[0][ks], acc0);
      acc1 = MFMA16(ah[ks], Bf[1][ks], acc1);
    }
    #pragma unroll
    for (int r = 0; r < 4; r++){
      float p = fmaxf(acc0[r] + b1v[0], 0.f) * w2v[0]
              + fmaxf(acc1[r] + b1v[1], 0.f) * w2v[1];
      p += __shfl_xor(p, 1);
      p += __shfl_xor(p, 2);
      p += __shfl_xor(p, 4);
      p += __shfl_xor(p, 8);
      if (lr == 0) partial[w4][Mt*16 + lq*4 + r] = p;
    }
  }
  __syncthreads();
  if (tid < 64){
    long row = rowbase + tid;
    int t = (int)(row >> 10), n = (int)(row & 1023);
    out[(size_t)n*TN + t] = partial[0][tid] + partial[1][tid]
                          + partial[2][tid] + partial[3][tid] + b2s;
  }
}

extern "C" void kernel_launch(void* const* d_in, const int* in_sizes, int n_in,
                              void* d_out, int out_size, void* d_ws, size_t ws_size,
                              hipStream_t stream)
{
  const float* x   = (const float*)d_in[0];
  const float* e1w = (const float*)d_in[1];
  const float* e1b = (const float*)d_in[2];
  const float* e2w = (const float*)d_in[3];
  const float* e2b = (const float*)d_in[4];
  const float* wih = (const float*)d_in[5];
  const float* whh = (const float*)d_in[6];
  const float* d1w = (const float*)d_in[7];
  const float* d1b = (const float*)d_in[8];
  const float* d2w = (const float*)d_in[9];
  const float* d2b = (const float*)d_in[10];
  float* out = (float*)d_out;

  if (ws_size < ((size_t)256 << 20)) return;   // ws guard (rounds 1-2 crashed on ws overflow)

  char* ws = (char*)d_ws;
  unsigned short* bufA = (unsigned short*)ws;                            // 128 MiB
  unsigned short* bufB = (unsigned short*)(ws + (((size_t)128) << 20));  // 128 MiB

  hipLaunchKernelGGL(enc_kernel, dim3(8192), dim3(256), 0, stream, x, e1w, e1b, e2w, e2b, bufA, bufB);
  hipLaunchKernelGGL(lstm_kernel, dim3(256), dim3(512), 0, stream, bufA, bufB, wih, whh);
  hipLaunchKernelGGL(dec_kernel, dim3(8192), dim3(256), 0, stream, bufA, bufB, d1w, d1b, d2w, d2b, out);
}

// Round 8
// 676.991 us; speedup vs baseline: 1.6842x; 1.0045x over previous
//
#include <hip/hip_runtime.h>
#include <hip/hip_fp16.h>
#include <stdint.h>

// Bidirectional LSTM: N=1024, T=512, H=128; enc 2->128->128; dec 256->128->1.
// fp16 MFMA (fp32 accum). ws = 256 MiB:
//   bufA 128MiB: feat -> overwritten in place with relu(h_fw)   [t][n][128] fp16
//   bufB 128MiB: feat -> overwritten in place with relu(h_bw)   [t][n][128] fp16
// LSTM: 256 blocks x 512 thr, 8 samples/block (A/C rows {0,1,4,5,...}).
// Round-8: software pipeline — step t's elementwise VALU overlaps step t+1's
// feat-part MFMAs (independent via 2-deep feat prefetch + double accumulator).
// Per-value FP op order unchanged vs round 7 -> absmax must stay 2.441406e-4.

#define TN 512
#define NB 1024

typedef __attribute__((ext_vector_type(8))) _Float16 f16x8;
typedef __attribute__((ext_vector_type(4))) float f32x4;

#define MFMA16(a,b,c) __builtin_amdgcn_mfma_f32_16x16x32_f16(a,b,c,0,0,0)
#define RCP(x) __builtin_amdgcn_rcpf(x)

__device__ __forceinline__ f16x8 cvt_frag(const float* p){
  f32x4 a = *(const f32x4*)p;
  f32x4 b = *(const f32x4*)(p+4);
  f16x8 h;
  h[0]=(_Float16)a[0]; h[1]=(_Float16)a[1]; h[2]=(_Float16)a[2]; h[3]=(_Float16)a[3];
  h[4]=(_Float16)b[0]; h[5]=(_Float16)b[1]; h[6]=(_Float16)b[2]; h[7]=(_Float16)b[3];
  return h;
}

__device__ __forceinline__ unsigned short f2h(float f){
  return __half_as_ushort(__float2half(f));
}

// ---------------- K0: encoder -> feat fp16 [t][n][128], written to BOTH copies ----------------
__global__ __launch_bounds__(256) void enc_kernel(
    const float* __restrict__ x,  const float* __restrict__ e1w,
    const float* __restrict__ e1b,const float* __restrict__ e2w,
    const float* __restrict__ e2b,
    unsigned short* __restrict__ featA, unsigned short* __restrict__ featB)
{
  __shared__ float xs[64][2];
  __shared__ unsigned int A32[64][68];   // r1 fp16 pairs, row stride 272B
  int tid = threadIdx.x;
  long rowbase = (long)blockIdx.x * 64;  // row = t*1024 + n
  if (tid < 128){
    int i = tid >> 1, cc = tid & 1;
    long row = rowbase + i;
    int t = (int)(row >> 10), n = (int)(row & 1023);
    xs[i][cc] = x[((size_t)n * TN + t) * 2 + cc];
  }
  int w4 = tid >> 6, lane = tid & 63, lq = lane >> 4, lr = lane & 15;
  f16x8 Bf[2][4];
  float b2v[2];
  #pragma unroll
  for (int nt2 = 0; nt2 < 2; nt2++){
    int col = (w4*2 + nt2)*16 + lr;
    b2v[nt2] = e2b[col];
    #pragma unroll
    for (int ks = 0; ks < 4; ks++)
      Bf[nt2][ks] = cvt_frag(e2w + col*128 + ks*32 + lq*8);
  }
  int q = tid >> 6, dp = tid & 63;
  float w00 = e1w[4*dp], w01 = e1w[4*dp+1], w10 = e1w[4*dp+2], w11 = e1w[4*dp+3];
  float b0 = e1b[2*dp], b1 = e1b[2*dp+1];
  __syncthreads();
  #pragma unroll
  for (int rr = 0; rr < 16; rr++){
    int r = q*16 + rr;
    float x0 = xs[r][0], x1 = xs[r][1];
    float v0 = fmaxf(w00*x0 + w01*x1 + b0, 0.f);
    float v1 = fmaxf(w10*x0 + w11*x1 + b1, 0.f);
    A32[r][dp] = (unsigned int)f2h(v0) | ((unsigned int)f2h(v1) << 16);
  }
  __syncthreads();
  #pragma unroll
  for (int Mt = 0; Mt < 4; Mt++){
    f16x8 ah[4];
    #pragma unroll
    for (int ks = 0; ks < 4; ks++)
      ah[ks] = *(const f16x8*)((const unsigned short*)&A32[Mt*16+lr][0] + ks*32 + lq*8);
    f32x4 acc0 = {0.f,0.f,0.f,0.f}, acc1 = {0.f,0.f,0.f,0.f};
    #pragma unroll
    for (int ks = 0; ks < 4; ks++){
      acc0 = MFMA16(ah[ks], Bf[0][ks], acc0);
      acc1 = MFMA16(ah[ks], Bf[1][ks], acc1);
    }
    #pragma unroll
    for (int r = 0; r < 4; r++){
      size_t row = (size_t)(rowbase + Mt*16 + lq*4 + r);
      unsigned short v0 = f2h(acc0[r] + b2v[0]);
      unsigned short v1 = f2h(acc1[r] + b2v[1]);
      featA[row*128 + (w4*2+0)*16 + lr] = v0;
      featA[row*128 + (w4*2+1)*16 + lr] = v1;
      featB[row*128 + (w4*2+0)*16 + lr] = v0;
      featB[row*128 + (w4*2+1)*16 + lr] = v1;
    }
  }
}

// ---------------- K1: persistent bidirectional LSTM (software-pipelined) ----------------
// 256 blocks x 512 thr; block b: dir=b>>7, samples n0..n0+7.
// Wave w: gate tiles {i,f,g,o} for hidden dims [16w,16w+16); weights resident.
// STEP(P): ACCC holds feat(t) part on entry; add h(t-1) part; meanwhile build
// ACCN = feat(t+1) part from PFC, interleaved with elementwise; prefetch
// feat(t+2) into PFN.
#define LSTM_STEP(P, ACCC, ACCN, PFC, PFN) do { \
    _Pragma("unroll") \
    for (int ks = 0; ks < 4; ks++) PFN[ks] = *(const uint4*)(fpp + ks*32); \
    fpp += dstep; \
    f16x8 ah[4]; \
    _Pragma("unroll") \
    for (int ks = 0; ks < 4; ks++) ah[ks] = *(const f16x8*)&hbS[P][smr][ks*32 + lq*8]; \
    _Pragma("unroll") \
    for (int G = 0; G < 4; G++){ \
      _Pragma("unroll") \
      for (int ks = 0; ks < 4; ks++) ACCC[G] = MFMA16(ah[ks], wg[G][4+ks], ACCC[G]); \
    } \
    /* interleave: next-step feat MFMAs with this-step elementwise */ \
    _Pragma("unroll") \
    for (int G = 0; G < 4; G++) ACCN[G] = MFMA16(*(const f16x8*)&PFC[0], wg[G][0], zero4); \
    float si0 = RCP(1.f + __expf(-ACCC[0][0])); \
    float si1 = RCP(1.f + __expf(-ACCC[0][1])); \
    _Pragma("unroll") \
    for (int G = 0; G < 4; G++) ACCN[G] = MFMA16(*(const f16x8*)&PFC[1], wg[G][1], ACCN[G]); \
    float sf0 = RCP(1.f + __expf(-ACCC[1][0])); \
    float sf1 = RCP(1.f + __expf(-ACCC[1][1])); \
    _Pragma("unroll") \
    for (int G = 0; G < 4; G++) ACCN[G] = MFMA16(*(const f16x8*)&PFC[2], wg[G][2], ACCN[G]); \
    float tg0 = 1.f - 2.f*RCP(__expf(2.f*ACCC[2][0]) + 1.f); \
    float tg1 = 1.f - 2.f*RCP(__expf(2.f*ACCC[2][1]) + 1.f); \
    float so0 = RCP(1.f + __expf(-ACCC[3][0])); \
    float so1 = RCP(1.f + __expf(-ACCC[3][1])); \
    _Pragma("unroll") \
    for (int G = 0; G < 4; G++) ACCN[G] = MFMA16(*(const f16x8*)&PFC[3], wg[G][3], ACCN[G]); \
    c[0] = sf0*c[0] + si0*tg0; \
    c[1] = sf1*c[1] + si1*tg1; \
    float tc0 = 1.f - 2.f*RCP(__expf(2.f*c[0]) + 1.f); \
    float tc1 = 1.f - 2.f*RCP(__expf(2.f*c[1]) + 1.f); \
    float hv0 = so0*tc0, hv1 = so1*tc1; \
    unsigned short hh0 = f2h(hv0), hh1 = f2h(hv1); \
    hbS[(P)^1][lq*2+0][w*16 + lr] = hh0; \
    hbS[(P)^1][lq*2+1][w*16 + lr] = hh1; \
    op[0]   = (hv0 > 0.f) ? hh0 : (unsigned short)0; \
    op[128] = (hv1 > 0.f) ? hh1 : (unsigned short)0; \
    op += dstep; \
    __syncthreads(); \
  } while(0)

__global__ __launch_bounds__(512, 2) void lstm_kernel(
    unsigned short* bufA, unsigned short* bufB,
    const float* __restrict__ wih, const float* __restrict__ whh)
{
  __shared__ __align__(16) unsigned short hbS[2][8][136];   // h double-buffer, 4352 B
  int tid = threadIdx.x, b = blockIdx.x;
  int dir = b >> 7, n0 = (b & 127) << 3;
  int w = tid >> 6, lane = tid & 63, lq = lane >> 4, lr = lane & 15;
  unsigned short* buf = dir ? bufB : bufA;

  // resident fp16 weight fragments: k 0..127 = w_ih (feat), 128..255 = w_hh (h)
  f16x8 wg[4][8];
  #pragma unroll
  for (int G = 0; G < 4; G++){
    int gate = G*128 + w*16 + lr;
    #pragma unroll
    for (int ks = 0; ks < 8; ks++){
      const float* src = (ks < 4) ? (wih + (size_t)gate*128 + ks*32 + lq*8)
                                  : (whh + (size_t)gate*128 + (ks-4)*32 + lq*8);
      wg[G][ks] = cvt_frag(src);
    }
  }

  for (int i = tid; i < 1088; i += 512) ((unsigned int*)hbS)[i] = 0u;

  // A-row R carries sample ((R>>2)<<1)|(R&1); this lane reads A row lr.
  int smr = ((lr >> 2) << 1) | (lr & 1);
  float c[2] = {0.f, 0.f};
  const f32x4 zero4 = {0.f, 0.f, 0.f, 0.f};
  int t0 = dir ? (TN-1) : 0;
  long dstep = dir ? -(long)(NB*128) : (long)(NB*128);

  // running feat pointer (this lane's A-row smr, k-chunk base lq*8)
  const unsigned short* fpp = buf + ((size_t)t0*NB + n0 + smr)*128 + lq*8;
  uint4 pfA[4], pfB[4];
  #pragma unroll
  for (int ks = 0; ks < 4; ks++) pfB[ks] = *(const uint4*)(fpp + ks*32);   // feat(t0)
  fpp += dstep;
  #pragma unroll
  for (int ks = 0; ks < 4; ks++) pfA[ks] = *(const uint4*)(fpp + ks*32);   // feat(t1)
  fpp += dstep;
  // Boundary over-reads (last prefetches reach t0 +/- 513 steps) stay inside
  // ws: fw runs into bufB's range; bw runs into bufA's. Values are dead.

  // prologue: accA = feat(t0) part
  f32x4 accA[4], accB[4];
  #pragma unroll
  for (int G = 0; G < 4; G++) accA[G] = MFMA16(*(const f16x8*)&pfB[0], wg[G][0], zero4);
  #pragma unroll
  for (int ks = 1; ks < 4; ks++){
    #pragma unroll
    for (int G = 0; G < 4; G++) accA[G] = MFMA16(*(const f16x8*)&pfB[ks], wg[G][ks], accA[G]);
  }

  // running output pointer: sample lq*2 (+1 via offset 128), dim w*16+lr
  unsigned short* op = buf + ((size_t)t0*NB + n0 + lq*2)*128 + (w*16 + lr);
  __syncthreads();

  for (int s2 = 0; s2 < TN/2; s2++){
    LSTM_STEP(0, accA, accB, pfA, pfB);
    LSTM_STEP(1, accB, accA, pfB, pfA);
  }
}

// ---------------- K2: decoder (fp16 MFMA, K=256); inputs already relu'd ----------------
__global__ __launch_bounds__(256) void dec_kernel(
    const unsigned short* __restrict__ hfw, const unsigned short* __restrict__ hbw,
    const float* __restrict__ d1w, const float* __restrict__ d1b,
    const float* __restrict__ d2w, const float* __restrict__ d2b,
    float* __restrict__ out)
{
  __shared__ unsigned short A[64][264];  // [hfw||hbw], row stride 528B
  __shared__ float partial[4][64];
  int tid = threadIdx.x;
  long rowbase = (long)blockIdx.x * 64;
  #pragma unroll
  for (int u = 0; u < 8; u++){
    int chunk = u*256 + tid;             // 0..2047
    int row = chunk >> 5, seg = chunk & 31;
    const unsigned short* src = (seg < 16)
        ? (hfw + ((size_t)(rowbase + row))*128 + seg*8)
        : (hbw + ((size_t)(rowbase + row))*128 + (seg-16)*8);
    *(uint4*)&A[row][seg*8] = *(const uint4*)src;
  }
  int w4 = tid >> 6, lane = tid & 63, lq = lane >> 4, lr = lane & 15;
  f16x8 Bf[2][8];
  float b1v[2], w2v[2];
  #pragma unroll
  for (int nt2 = 0; nt2 < 2; nt2++){
    int col = (w4*2 + nt2)*16 + lr;
    b1v[nt2] = d1b[col];
    w2v[nt2] = d2w[col];
    #pragma unroll
    for (int ks = 0; ks < 8; ks++)
      Bf[nt2][ks] = cvt_frag(d1w + col*256 + ks*32 + lq*8);
  }
  float b2s = d2b[0];
  __syncthreads();
  #pragma unroll
  for (int Mt = 0; Mt < 4; Mt++){
    f16x8 ah[8];
    #pragma unroll
    for (int ks = 0; ks < 8; ks++)
      ah[ks] = *(const f16x8*)&A[Mt*16+lr][ks*32 + lq*8];
    f32x4 acc0 = {0.f,0.f,0.f,0.f}, acc1 = {0.f,0.f,0.f,0.f};
    #pragma unroll
    for (int ks = 0; ks < 8; ks++){
      acc0 = MFMA16(ah[ks], Bf[0][ks], acc0);
      acc1 = MFMA16(ah[ks], Bf[1][ks], acc1);
    }
    #pragma unroll
    for (int r = 0; r < 4; r++){
      float p = fmaxf(acc0[r] + b1v[0], 0.f) * w2v[0]
              + fmaxf(acc1[r] + b1v[1], 0.f) * w2v[1];
      p += __shfl_xor(p, 1);
      p += __shfl_xor(p, 2);
      p += __shfl_xor(p, 4);
      p += __shfl_xor(p, 8);
      if (lr == 0) partial[w4][Mt*16 + lq*4 + r] = p;
    }
  }
  __syncthreads();
  if (tid < 64){
    long row = rowbase + tid;
    int t = (int)(row >> 10), n = (int)(row & 1023);
    out[(size_t)n*TN + t] = partial[0][tid] + partial[1][tid]
                          + partial[2][tid] + partial[3][tid] + b2s;
  }
}

extern "C" void kernel_launch(void* const* d_in, const int* in_sizes, int n_in,
                              void* d_out, int out_size, void* d_ws, size_t ws_size,
                              hipStream_t stream)
{
  const float* x   = (const float*)d_in[0];
  const float* e1w = (const float*)d_in[1];
  const float* e1b = (const float*)d_in[2];
  const float* e2w = (const float*)d_in[3];
  const float* e2b = (const float*)d_in[4];
  const float* wih = (const float*)d_in[5];
  const float* whh = (const float*)d_in[6];
  const float* d1w = (const float*)d_in[7];
  const float* d1b = (const float*)d_in[8];
  const float* d2w = (const float*)d_in[9];
  const float* d2b = (const float*)d_in[10];
  float* out = (float*)d_out;

  if (ws_size < ((size_t)256 << 20)) return;   // ws guard (rounds 1-2 crashed on ws overflow)

  char* ws = (char*)d_ws;
  unsigned short* bufA = (unsigned short*)ws;                            // 128 MiB
  unsigned short* bufB = (unsigned short*)(ws + (((size_t)128) << 20));  // 128 MiB

  hipLaunchKernelGGL(enc_kernel, dim3(8192), dim3(256), 0, stream, x, e1w, e1b, e2w, e2b, bufA, bufB);
  hipLaunchKernelGGL(lstm_kernel, dim3(256), dim3(512), 0, stream, bufA, bufB, wih, whh);
  hipLaunchKernelGGL(dec_kernel, dim3(8192), dim3(256), 0, stream, bufA, bufB, d1w, d1b, d2w, d2b, out);
}